// Round 20
// baseline (207.577 us; speedup 1.0000x reference)
//
#include <hip/hip_runtime.h>

typedef unsigned short u16;
typedef unsigned int u32;
typedef __attribute__((ext_vector_type(8))) short short8;
typedef __attribute__((ext_vector_type(4))) float f32x4;
typedef __attribute__((ext_vector_type(4))) u16 u16x4;

#define LOG2E 1.4426950408889634f
#define SCL2 (0.125f * LOG2E)

static __device__ __forceinline__ float bf2f(u16 u) {
    return __uint_as_float(((unsigned)u) << 16);
}
static __device__ __forceinline__ u16 f2bf(float f) {
    unsigned u = __float_as_uint(f);
    unsigned r = (u + 0x7FFF + ((u >> 16) & 1)) >> 16;
    return (u16)r;
}
static __device__ __forceinline__ u32 cvtpk(float lo, float hi) {
    u32 r;
    asm("v_cvt_pk_bf16_f32 %0, %1, %2" : "=v"(r) : "v"(lo), "v"(hi));
    return r;
}
static __device__ __forceinline__ f32x4 mfma16(short8 a, short8 b, f32x4 c) {
    return __builtin_amdgcn_mfma_f32_16x16x32_bf16(a, b, c, 0, 0, 0);
}
static __device__ __forceinline__ void gload_lds16(const void* g, void* l) {
    __builtin_amdgcn_global_load_lds(
        (const __attribute__((address_space(1))) void*)g,
        (__attribute__((address_space(3))) void*)l, 16, 0, 0);
}

#define GBAR() do { asm volatile("" ::: "memory"); __builtin_amdgcn_s_barrier(); asm volatile("" ::: "memory"); } while (0)
#define LGW()  do { asm volatile("s_waitcnt lgkmcnt(0)" ::: "memory"); __builtin_amdgcn_sched_barrier(0); } while (0)

// ---------------- ALL prep in ONE dispatch ----------------
// id < 10240: weight prep (fold/transpose, 32x32 tiles)
// id in [10240, 12288): cast x fp32->bf16; id >= 12288: rope table pack
__global__ void prep_all_kernel(
    const float* __restrict__ x, const float* __restrict__ cosb, const float* __restrict__ sinb,
    const float* __restrict__ Wq, const float* __restrict__ Wk,
    const float* __restrict__ Wv, const float* __restrict__ Wo,
    const float* __restrict__ qA, const float* __restrict__ qB,
    const float* __restrict__ kA, const float* __restrict__ kB,
    const float* __restrict__ vA, const float* __restrict__ vB,
    u16* __restrict__ xb, u32* __restrict__ tbl,
    u16* __restrict__ WqkvT, u16* __restrict__ WoT) {
    const int id = blockIdx.x;
    const int tx = threadIdx.x, ty = threadIdx.y;
    if (id >= 10240) {
        const int tid = ty * 32 + tx;
        if (id >= 12288) {
            const int i = ((id - 12288) * 1024 + tid) * 4;
#pragma unroll
            for (int j = 0; j < 4; ++j)
                tbl[i + j] = (u32)f2bf(cosb[i + j]) | ((u32)f2bf(sinb[i + j]) << 16);
        } else {
            const int i = ((id - 10240) * 1024 + tid) * 4;
            f32x4 v = *(const f32x4*)&x[i];
            u16x4 o;
            o.x = f2bf(v.x); o.y = f2bf(v.y); o.z = f2bf(v.z); o.w = f2bf(v.w);
            *(u16x4*)&xb[i] = o;
        }
        return;
    }
    __shared__ float tile[32][33];
    __shared__ float As[32][17];
    __shared__ float Bs[16][33];
    const float *W, *A = nullptr, *Bm = nullptr;
    u16* dst;
    int C, bx, by;
    bool fold = true;
    if (id < 4096)      { W = Wq; A = qA; Bm = qB; dst = WqkvT; C = 2048; bx = id & 63; by = id >> 6; }
    else if (id < 5120) { int t = id - 4096; W = Wk; A = kA; Bm = kB; dst = WqkvT + (size_t)2048 * 2048; C = 512; bx = t & 15; by = t >> 4; }
    else if (id < 6144) { int t = id - 5120; W = Wv; A = vA; Bm = vB; dst = WqkvT + (size_t)2560 * 2048; C = 512; bx = t & 15; by = t >> 4; }
    else                { int t = id - 6144; W = Wo; dst = WoT; C = 2048; bx = t & 63; by = t >> 6; fold = false; }
    const int c0 = bx * 32, r0 = by * 32;
    tile[ty][tx] = W[(size_t)(r0 + ty) * C + c0 + tx];
    if (fold) {
        if (tx < 16) As[ty][tx] = A[(r0 + ty) * 16 + tx];
        if (ty < 16) Bs[ty][tx] = Bm[(size_t)ty * C + c0 + tx];
    }
    __syncthreads();
    float v = tile[tx][ty];
    if (fold) {
        float acc = 0.0f;
#pragma unroll
        for (int rr = 0; rr < 16; ++rr) acc += As[tx][rr] * Bs[rr][ty];
        v += 2.0f * acc;
    }
    dst[(size_t)(c0 + ty) * 2048 + r0 + tx] = f2bf(v);
}

// ---------------- QKV GEMM: 256x192 tile, BK=64, 8 waves, 8-phase, FULL-CHIP grid ------
__global__ __launch_bounds__(512) void gemm256_qkv_kernel(
    const u16* __restrict__ A, const u16* __restrict__ Bt, u16* __restrict__ Cq,
    u16* __restrict__ Ck, u16* __restrict__ Vt, const u32* __restrict__ ropetbl) {
    constexpr int K = 2048, NT = 32;
    __shared__ u16 Asl[2][256 * 64];
    __shared__ u16 Bsl[2][192 * 64];
    const int tid = threadIdx.x;
    const int wid = tid >> 6, lane = tid & 63;
    const int flat = blockIdx.x;
    const int m = ((flat & 7) << 1) + ((flat >> 3) & 1);   // XCD m-chunking
    const int n = flat >> 4;
    const int mbase = m * 256, nbase = n * 192;
    const int wrow = (wid >> 2) * 128, wcol = (wid & 3) * 48;
    const int fr = lane & 15, hi = lane >> 4;
    const int rs2 = fr & 7;
    f32x4 acc[8][3] = {};
    short8 Af[4][2], Bf[3][2];
    const u16* Ag = A + (size_t)mbase * K;
    const u16* Bg = Bt + (size_t)nbase * K;

    auto HT = [&](int t, int j) {
        if (t >= NT) return;
        const int buf = t & 1;
        const bool isA = (j < 4);
        u16* l = isA ? &Asl[buf][0] : &Bsl[buf][0];
        const u16* g = isA ? Ag : Bg;
        const int rbase = (isA ? j : (j - 4)) * 64;
        const int row = rbase + (tid >> 3);
        const int sl = (tid & 7) ^ ((tid >> 3) & 7);
        gload_lds16(&g[(size_t)row * K + t * 64 + sl * 8],
                    &l[rbase * 64 + wid * 512]);
    };
    auto DSA = [&](int mo, int buf) {
#pragma unroll
        for (int mi = 0; mi < 4; ++mi)
#pragma unroll
            for (int ks = 0; ks < 2; ++ks)
                Af[mi][ks] = *(const short8*)&Asl[buf][(wrow + (mo + mi) * 16 + fr) * 64 +
                                                       (((ks * 4 + hi) ^ rs2) * 8)];
    };
    auto DSB = [&](int nlo, int nhi, int buf) {
#pragma unroll
        for (int ni = 0; ni < 3; ++ni) {
            if (ni < nlo || ni >= nhi) continue;
#pragma unroll
            for (int ks = 0; ks < 2; ++ks)
                Bf[ni][ks] = *(const short8*)&Bsl[buf][(wcol + ni * 16 + fr) * 64 +
                                                       (((ks * 4 + hi) ^ rs2) * 8)];
        }
    };
    auto MFq = [&](int mo, int nlo, int nhi) {
        __builtin_amdgcn_s_setprio(1);
#pragma unroll
        for (int mi = 0; mi < 4; ++mi)
#pragma unroll
            for (int ni = 0; ni < 3; ++ni) {
                if (ni < nlo || ni >= nhi) continue;
#pragma unroll
                for (int ks = 0; ks < 2; ++ks)
                    acc[mo + mi][ni] = mfma16(Af[mi][ks], Bf[ni][ks], acc[mo + mi][ni]);
            }
        __builtin_amdgcn_s_setprio(0);
    };

    HT(0, 0); HT(0, 1); HT(0, 2); HT(0, 3); HT(0, 4); HT(0, 5); HT(0, 6);
    HT(1, 0); HT(1, 1); HT(1, 2); HT(1, 3);
    asm volatile("s_waitcnt vmcnt(4)" ::: "memory");
    GBAR();

#pragma unroll 1
    for (int i = 0; i < NT / 2; ++i) {
        const int t = 2 * i;
        DSA(0, 0); DSB(0, 2, 0); HT(t + 1, 4); HT(t + 1, 5);
        GBAR(); LGW(); MFq(0, 0, 2); GBAR();
        DSB(2, 3, 0); HT(t + 1, 6);
        GBAR(); LGW(); MFq(0, 2, 3); GBAR();
        DSA(4, 0);
        GBAR(); LGW(); MFq(4, 0, 2); GBAR();
        HT(t + 2, 0); HT(t + 2, 1); HT(t + 2, 2); HT(t + 2, 3);
        GBAR(); LGW(); MFq(4, 2, 3);
        if (t + 2 < NT) { asm volatile("s_waitcnt vmcnt(4)" ::: "memory"); }
        else            { asm volatile("s_waitcnt vmcnt(0)" ::: "memory"); }
        GBAR();
        DSA(0, 1); DSB(0, 2, 1); HT(t + 2, 4); HT(t + 2, 5);
        GBAR(); LGW(); MFq(0, 0, 2); GBAR();
        DSB(2, 3, 1); HT(t + 2, 6);
        GBAR(); LGW(); MFq(0, 2, 3); GBAR();
        DSA(4, 1);
        GBAR(); LGW(); MFq(4, 0, 2); GBAR();
        HT(t + 3, 0); HT(t + 3, 1); HT(t + 3, 2); HT(t + 3, 3);
        GBAR(); LGW(); MFq(4, 2, 3);
        if (t + 3 < NT)          { asm volatile("s_waitcnt vmcnt(4)" ::: "memory"); }
        else if (i < NT / 2 - 1) { asm volatile("s_waitcnt vmcnt(0)" ::: "memory"); }
        GBAR();
    }

    const int rb = mbase + wrow + (hi << 2);
#pragma unroll
    for (int ni = 0; ni < 3; ++ni) {
        const int colc = nbase + wcol + ni * 16;
        if (colc >= 2560) {
            const int feat = colc - 2560 + fr;
#pragma unroll
            for (int mi = 0; mi < 8; ++mi) {
                u16x4 w;
#pragma unroll
                for (int j = 0; j < 4; ++j) w[j] = f2bf(acc[mi][ni][j]);
                *(u16x4*)&Vt[(size_t)feat * 4096 + rb + mi * 16] = w;
            }
        } else {
            u16* C; int cs, ccol; float scale;
            if (colc < 2048) { C = Cq; cs = 2048; ccol = colc + fr;        scale = SCL2; }
            else             { C = Ck; cs = 512;  ccol = colc - 2048 + fr; scale = 1.0f; }
            const bool odd = (lane & 1);
            const int i0 = ((colc & 63) >> 1) + (fr >> 1);
#pragma unroll
            for (int mi = 0; mi < 8; ++mi)
#pragma unroll
                for (int j = 0; j < 4; ++j) {
                    const int row = rb + mi * 16 + j;
                    u32 cspk = ropetbl[(row & 1023) * 32 + i0];
                    float cv = bf2f((u16)cspk), sv = bf2f((u16)(cspk >> 16));
                    float v = acc[mi][ni][j];
                    float p = __shfl_xor(v, 1);
                    float r = (odd ? (p * sv + v * cv) : (v * cv - p * sv)) * scale;
                    float rp = __shfl_xor(r, 1);   // partner's (odd-col) result
                    if (!odd) *(u32*)&C[(size_t)row * cs + ccol] = cvtpk(r, rp);
                }
        }
    }
}

// ---------------- Wo GEMM: 128x128, BK=64, dbuf DMA + counted vmcnt + T2 swizzle --------
template <int CN>
__global__ __launch_bounds__(256) void gemm_kernel(
    const u16* __restrict__ A, const u16* __restrict__ Bt, float* __restrict__ C0, int Nn) {
    constexpr int K = 2048;
    constexpr int NT = K / 64;
    __shared__ u16 As[2][128 * 64];
    __shared__ u16 Bs[2][128 * 64];
    const int tid = threadIdx.x;
    const int wid = tid >> 6, lane = tid & 63;
    const int flat = blockIdx.y * gridDim.x + blockIdx.x;
    const int xcd = flat & 7, local = flat >> 3;
    const int mbase = (((xcd & 3) << 3) + (local & 7)) * 128;
    const int nbase = ((xcd >> 2) * CN + (local >> 3)) * 128;
    const int wrow = (wid >> 1) * 64, wcol = (wid & 1) * 64;
    const int fr = lane & 15, hi = lane >> 4;
    const int l8 = lane >> 3;
    const int swc = ((lane & 7) ^ l8) * 8;
    const int rs = fr & 7;
    f32x4 acc[4][4] = {};
    const u16* Ag = A + (size_t)mbase * K;
    const u16* Bg = Bt + (size_t)nbase * K;

    auto STAGE = [&](int kt, int buf) {
#pragma unroll
        for (int i = 0; i < 4; ++i) {
            const int r8 = (i * 4 + wid) * 8;
            gload_lds16(&Ag[(size_t)(r8 + l8) * K + kt * 64 + swc], &As[buf][r8 * 64]);
            gload_lds16(&Bg[(size_t)(r8 + l8) * K + kt * 64 + swc], &Bs[buf][r8 * 64]);
        }
    };

    STAGE(0, 0);
    for (int kt = 0; kt < NT; ++kt) {
        const int cur = kt & 1;
        if (kt < NT - 1) {
            STAGE(kt + 1, cur ^ 1);
            asm volatile("s_waitcnt vmcnt(8)" ::: "memory");
        } else {
            asm volatile("s_waitcnt vmcnt(0)" ::: "memory");
        }
        __builtin_amdgcn_s_barrier();
#pragma unroll
        for (int ks = 0; ks < 2; ++ks) {
            short8 af[4], bfr[4];
#pragma unroll
            for (int i = 0; i < 4; ++i) {
                const int arow = wrow + i * 16 + fr;
                const int brow = wcol + i * 16 + fr;
                af[i]  = *(const short8*)&As[cur][arow * 64 + (((ks * 4 + hi) ^ rs) * 8)];
                bfr[i] = *(const short8*)&Bs[cur][brow * 64 + (((ks * 4 + hi) ^ rs) * 8)];
            }
#pragma unroll
            for (int mi = 0; mi < 4; ++mi)
#pragma unroll
                for (int ni = 0; ni < 4; ++ni)
                    acc[mi][ni] = mfma16(af[mi], bfr[ni], acc[mi][ni]);
        }
        __builtin_amdgcn_s_barrier();
    }
    const int rb = mbase + wrow + (hi << 2);
    const int cb = nbase + wcol + fr;
#pragma unroll
    for (int mi = 0; mi < 4; ++mi)
#pragma unroll
        for (int j = 0; j < 4; ++j) {
            const size_t ro = (size_t)(rb + mi * 16 + j) * Nn;
#pragma unroll
            for (int ni = 0; ni < 4; ++ni) C0[ro + cb + ni * 16] = acc[mi][ni][j];
        }
}

// ---------------- attention tile step (T5 setprio on MFMA clusters) ----------------
template <bool DIAG>
static __device__ __forceinline__ void attn_tile_step(
    const u16* __restrict__ Ksb, const u16* __restrict__ Vsb,
    const short8* qf, f32x4* o, float& m, float& l,
    int sq, int kvb, int wid, int fr, int hi) {
    f32x4 s[4];
    const int sw = fr & 7;
#pragma unroll
    for (int mi = 0; mi < 4; ++mi) {
        if (!DIAG || mi <= wid) {
            const int row = (mi * 16 + fr) * 64;
            short8 kf0 = *(const short8*)&Ksb[row + ((hi ^ sw) * 8)];
            short8 kf1 = *(const short8*)&Ksb[row + (((4 + hi) ^ sw) * 8)];
            f32x4 z = {};
            __builtin_amdgcn_s_setprio(1);
            z = mfma16(kf0, qf[0], z);
            z = mfma16(kf1, qf[1], z);
            __builtin_amdgcn_s_setprio(0);
#pragma unroll
            for (int j = 0; j < 4; ++j) {
                float val = z[j];
                if (DIAG && mi == wid && (kvb + mi * 16 + hi * 4 + j > sq)) val = -3.0e38f;
                s[mi][j] = val;
            }
        } else {
            s[mi][0] = -3.0e38f; s[mi][1] = -3.0e38f;
            s[mi][2] = -3.0e38f; s[mi][3] = -3.0e38f;
        }
    }
    float pmax = fmaxf(fmaxf(fmaxf(s[0][0], s[0][1]), fmaxf(s[0][2], s[0][3])),
                       fmaxf(fmaxf(s[1][0], s[1][1]), fmaxf(s[1][2], s[1][3])));
    pmax = fmaxf(pmax, fmaxf(fmaxf(fmaxf(s[2][0], s[2][1]), fmaxf(s[2][2], s[2][3])),
                             fmaxf(fmaxf(s[3][0], s[3][1]), fmaxf(s[3][2], s[3][3]))));
    pmax = fmaxf(pmax, __shfl_xor(pmax, 16));
    pmax = fmaxf(pmax, __shfl_xor(pmax, 32));
    if (__any(pmax > m + 8.0f)) {
        const float mnew = fmaxf(m, pmax);
        const float fsc = exp2f(m - mnew);
        l *= fsc;
        m = mnew;
#pragma unroll
        for (int dn = 0; dn < 4; ++dn)
#pragma unroll
            for (int j = 0; j < 4; ++j) o[dn][j] *= fsc;
    }
    float rs = 0.0f;
    u32 pk[4][2];
#pragma unroll
    for (int mi = 0; mi < 4; ++mi) {
        float p0 = exp2f(s[mi][0] - m);
        float p1 = exp2f(s[mi][1] - m);
        float p2 = exp2f(s[mi][2] - m);
        float p3 = exp2f(s[mi][3] - m);
        rs += (p0 + p1) + (p2 + p3);
        pk[mi][0] = cvtpk(p0, p1);
        pk[mi][1] = cvtpk(p2, p3);
    }
    rs += __shfl_xor(rs, 16);
    rs += __shfl_xor(rs, 32);
    l += rs;
    const int ksmax = DIAG ? (wid >> 1) : 1;
#pragma unroll
    for (int ks = 0; ks < 2; ++ks) {
        if (ks > ksmax) continue;
        u32 w0 = pk[2 * ks][0], w2 = pk[2 * ks + 1][0];
        u32 w1 = pk[2 * ks][1], w3 = pk[2 * ks + 1][1];
        asm volatile("v_permlane32_swap_b32 %0, %1" : "+v"(w0), "+v"(w2));
        asm volatile("v_permlane16_swap_b32 %0, %1" : "+v"(w0), "+v"(w2));
        asm volatile("v_permlane32_swap_b32 %0, %1" : "+v"(w1), "+v"(w3));
        asm volatile("v_permlane16_swap_b32 %0, %1" : "+v"(w1), "+v"(w3));
        union { u32 w[4]; short8 s8; } pu;
        pu.w[0] = w0; pu.w[1] = w1; pu.w[2] = w2; pu.w[3] = w3;
        short8 pf = pu.s8;
        __builtin_amdgcn_s_setprio(1);
#pragma unroll
        for (int dn = 0; dn < 4; ++dn) {
            const int row = (dn * 16 + fr) * 64;
            short8 vf = *(const short8*)&Vsb[row + (((ks * 4 + hi) ^ sw) * 8)];
            o[dn] = mfma16(vf, pf, o[dn]);
        }
        __builtin_amdgcn_s_setprio(0);
    }
}

// ---------------- causal GQA flash attention, 2 heads + paired q-tiles per block -------
__global__ __launch_bounds__(256) void attn_kernel(
    const u16* __restrict__ q, const u16* __restrict__ k, const u16* __restrict__ vt,
    u16* __restrict__ ctx) {
    __shared__ u16 Ks[2][64 * 64];
    __shared__ u16 Vs[2][64 * 64];
    const int flat = blockIdx.x + 8 * (blockIdx.y + 16 * blockIdx.z);
    const int c = flat & 7, t = flat >> 3;
    const int jp = t & 7;
    const int grp = c + 8 * (t >> 3);
    const int hp = grp & 15, b = grp >> 4;
    const int qtA = jp, qtB = 15 - jp;
    const int h0 = hp * 2;
    const int g = hp >> 1;
    const int tid = threadIdx.x, wid = tid >> 6, lane = tid & 63;
    const int fr = lane & 15, hi = lane >> 4, fk = hi * 8;
    const int sqA = qtA * 64 + wid * 16 + fr;
    const int sqB = qtB * 64 + wid * 16 + fr;
    short8 qA0[2], qB0[2], qA1[2], qB1[2];
    {
        const u16* pa = &q[((size_t)(b * 1024 + sqA)) * 2048 + h0 * 64];
        qA0[0] = *(const short8*)&pa[fk];      qA0[1] = *(const short8*)&pa[32 + fk];
        qA1[0] = *(const short8*)&pa[64 + fk]; qA1[1] = *(const short8*)&pa[96 + fk];
        const u16* pb = &q[((size_t)(b * 1024 + sqB)) * 2048 + h0 * 64];
        qB0[0] = *(const short8*)&pb[fk];      qB0[1] = *(const short8*)&pb[32 + fk];
        qB1[0] = *(const short8*)&pb[64 + fk]; qB1[1] = *(const short8*)&pb[96 + fk];
    }
    f32x4 oA0[4] = {}, oA1[4] = {}, oB0[4] = {}, oB1[4] = {};
    float mA0 = -3.0e38f, lA0 = 0.0f, mA1 = -3.0e38f, lA1 = 0.0f;
    float mB0 = -3.0e38f, lB0 = 0.0f, mB1 = -3.0e38f, lB1 = 0.0f;
    const u16* kbase = k + ((size_t)b * 1024) * 512 + g * 64;
    const u16* vbase = vt + ((size_t)(g * 64)) * 4096 + b * 1024;
    const int l8 = lane >> 3;
    const int sw8 = ((lane & 7) ^ l8) * 8;

    auto stage = [&](int kt, int buf) {
        const u16* kg = kbase + (size_t)(kt * 64) * 512;
        const u16* vg = vbase + kt * 64;
#pragma unroll
        for (int i = 0; i < 2; ++i) {
            const int r8 = (i * 4 + wid) * 8;
            gload_lds16(&kg[(size_t)(r8 + l8) * 512 + sw8], &Ks[buf][r8 * 64]);
            gload_lds16(&vg[(size_t)(r8 + l8) * 4096 + sw8], &Vs[buf][r8 * 64]);
        }
    };

    stage(0, 0);
    for (int kt = 0; kt <= qtB; ++kt) {
        const int cur = kt & 1;
        __syncthreads();
        if (kt < qtB) stage(kt + 1, cur ^ 1);
        const int kvb = kt * 64;
        if (kt < qtA) {
            attn_tile_step<false>(Ks[cur], Vs[cur], qA0, oA0, mA0, lA0, sqA, kvb, wid, fr, hi);
            attn_tile_step<false>(Ks[cur], Vs[cur], qA1, oA1, mA1, lA1, sqA, kvb, wid, fr, hi);
        } else if (kt == qtA) {
            attn_tile_step<true>(Ks[cur], Vs[cur], qA0, oA0, mA0, lA0, sqA, kvb, wid, fr, hi);
            attn_tile_step<true>(Ks[cur], Vs[cur], qA1, oA1, mA1, lA1, sqA, kvb, wid, fr, hi);
        }
        if (kt < qtB) {
            attn_tile_step<false>(Ks[cur], Vs[cur], qB0, oB0, mB0, lB0, sqB, kvb, wid, fr, hi);
            attn_tile_step<false>(Ks[cur], Vs[cur], qB1, oB1, mB1, lB1, sqB, kvb, wid, fr, hi);
        } else {
            attn_tile_step<true>(Ks[cur], Vs[cur], qB0, oB0, mB0, lB0, sqB, kvb, wid, fr, hi);
            attn_tile_step<true>(Ks[cur], Vs[cur], qB1, oB1, mB1, lB1, sqB, kvb, wid, fr, hi);
        }
    }
    auto emit = [&](const f32x4* o, float l, int sq, int h) {
        const float linv = 1.0f / l;
        const size_t obase = ((size_t)(b * 1024 + sq)) * 2048 + h * 64;
#pragma unroll
        for (int dn = 0; dn < 4; ++dn) {
            u16x4 w;
#pragma unroll
            for (int j = 0; j < 4; ++j) w[j] = f2bf(o[dn][j] * linv);
            *(u16x4*)&ctx[obase + dn * 16 + hi * 4] = w;
        }
    };
    emit(oA0, lA0, sqA, h0);
    emit(oA1, lA1, sqA, h0 + 1);
    emit(oB0, lB0, sqB, h0);
    emit(oB1, lB1, sqB, h0 + 1);
}

extern "C" void kernel_launch(void* const* d_in, const int* in_sizes, int n_in,
                              void* d_out, int out_size, void* d_ws, size_t ws_size,
                              hipStream_t stream) {
    const float* x    = (const float*)d_in[0];
    const float* fcos = (const float*)d_in[1];
    const float* fsin = (const float*)d_in[2];
    const float* Wq   = (const float*)d_in[3];
    const float* Wk   = (const float*)d_in[4];
    const float* Wv   = (const float*)d_in[5];
    const float* Wo   = (const float*)d_in[6];
    const float* qA   = (const float*)d_in[7];
    const float* qB   = (const float*)d_in[8];
    const float* kA   = (const float*)d_in[9];
    const float* kB   = (const float*)d_in[10];
    const float* vA   = (const float*)d_in[11];
    const float* vB   = (const float*)d_in[12];
    float* out = (float*)d_out;

    char* ws = (char*)d_ws;
    size_t off = 0;
    auto alloc = [&](size_t bytes) { char* p = ws + off; off += (bytes + 255) & ~(size_t)255; return p; };
    u16* xb     = (u16*)alloc((size_t)4096 * 2048 * 2);
    u16* WqkvT  = (u16*)alloc((size_t)3072 * 2048 * 2);
    u16* WoT    = (u16*)alloc((size_t)2048 * 2048 * 2);
    u16* qbuf   = (u16*)alloc((size_t)4096 * 2048 * 2);
    u16* kbuf   = (u16*)alloc((size_t)4096 * 512 * 2);
    u16* VT2    = (u16*)alloc((size_t)512 * 4096 * 2);   // V^T: [(g*64+d)][b*1024+s]
    u16* ctx    = (u16*)alloc((size_t)4096 * 2048 * 2);
    u32* rtbl   = (u32*)alloc((size_t)1024 * 32 * 4);

    // cast x + rope pack + ALL weight prep in ONE dispatch
    prep_all_kernel<<<12296, dim3(32, 32), 0, stream>>>(
        x, fcos, fsin, Wq, Wk, Wv, Wo, qA, qB, kA, kB, vA, vB,
        xb, rtbl, WqkvT, WoT);

    // QKV projection: 256x192 8-phase, 256 blocks (full chip), fused RoPE + V^T epilogue
    gemm256_qkv_kernel<<<dim3(256), 512, 0, stream>>>(xb, WqkvT, qbuf, kbuf, VT2, rtbl);

    attn_kernel<<<dim3(8, 16, 4), 256, 0, stream>>>(qbuf, kbuf, VT2, ctx);

    // Wo projection: 128x128 dbuf (proven — exactly one 8-phase kernel per iteration)
    gemm_kernel<8><<<dim3(32, 16), 256, 0, stream>>>(ctx, WoT, out, 2048);
}

// Round 21
// 192.325 us; speedup vs baseline: 1.0793x; 1.0793x over previous
//
#include <hip/hip_runtime.h>

typedef unsigned short u16;
typedef unsigned int u32;
typedef __attribute__((ext_vector_type(8))) short short8;
typedef __attribute__((ext_vector_type(4))) float f32x4;
typedef __attribute__((ext_vector_type(4))) u16 u16x4;

#define LOG2E 1.4426950408889634f
#define SCL2 (0.125f * LOG2E)

static __device__ __forceinline__ float bf2f(u16 u) {
    return __uint_as_float(((unsigned)u) << 16);
}
static __device__ __forceinline__ u16 f2bf(float f) {
    unsigned u = __float_as_uint(f);
    unsigned r = (u + 0x7FFF + ((u >> 16) & 1)) >> 16;
    return (u16)r;
}
static __device__ __forceinline__ u32 cvtpk(float lo, float hi) {
    u32 r;
    asm("v_cvt_pk_bf16_f32 %0, %1, %2" : "=v"(r) : "v"(lo), "v"(hi));
    return r;
}
static __device__ __forceinline__ f32x4 mfma16(short8 a, short8 b, f32x4 c) {
    return __builtin_amdgcn_mfma_f32_16x16x32_bf16(a, b, c, 0, 0, 0);
}
static __device__ __forceinline__ void gload_lds16(const void* g, void* l) {
    __builtin_amdgcn_global_load_lds(
        (const __attribute__((address_space(1))) void*)g,
        (__attribute__((address_space(3))) void*)l, 16, 0, 0);
}

#define GBAR() do { asm volatile("" ::: "memory"); __builtin_amdgcn_s_barrier(); asm volatile("" ::: "memory"); } while (0)
#define LGW()  do { asm volatile("s_waitcnt lgkmcnt(0)" ::: "memory"); __builtin_amdgcn_sched_barrier(0); } while (0)

// ---------------- ALL prep in ONE dispatch ----------------
// id < 10240: weight prep (fold/transpose, 32x32 tiles)
// id in [10240, 12288): cast x fp32->bf16; id >= 12288: rope table pack
__global__ void prep_all_kernel(
    const float* __restrict__ x, const float* __restrict__ cosb, const float* __restrict__ sinb,
    const float* __restrict__ Wq, const float* __restrict__ Wk,
    const float* __restrict__ Wv, const float* __restrict__ Wo,
    const float* __restrict__ qA, const float* __restrict__ qB,
    const float* __restrict__ kA, const float* __restrict__ kB,
    const float* __restrict__ vA, const float* __restrict__ vB,
    u16* __restrict__ xb, u32* __restrict__ tbl,
    u16* __restrict__ WqkvT, u16* __restrict__ WoT) {
    const int id = blockIdx.x;
    const int tx = threadIdx.x, ty = threadIdx.y;
    if (id >= 10240) {
        const int tid = ty * 32 + tx;
        if (id >= 12288) {
            const int i = ((id - 12288) * 1024 + tid) * 4;
#pragma unroll
            for (int j = 0; j < 4; ++j)
                tbl[i + j] = (u32)f2bf(cosb[i + j]) | ((u32)f2bf(sinb[i + j]) << 16);
        } else {
            const int i = ((id - 10240) * 1024 + tid) * 4;
            f32x4 v = *(const f32x4*)&x[i];
            u16x4 o;
            o.x = f2bf(v.x); o.y = f2bf(v.y); o.z = f2bf(v.z); o.w = f2bf(v.w);
            *(u16x4*)&xb[i] = o;
        }
        return;
    }
    __shared__ float tile[32][33];
    __shared__ float As[32][17];
    __shared__ float Bs[16][33];
    const float *W, *A = nullptr, *Bm = nullptr;
    u16* dst;
    int C, bx, by;
    bool fold = true;
    if (id < 4096)      { W = Wq; A = qA; Bm = qB; dst = WqkvT; C = 2048; bx = id & 63; by = id >> 6; }
    else if (id < 5120) { int t = id - 4096; W = Wk; A = kA; Bm = kB; dst = WqkvT + (size_t)2048 * 2048; C = 512; bx = t & 15; by = t >> 4; }
    else if (id < 6144) { int t = id - 5120; W = Wv; A = vA; Bm = vB; dst = WqkvT + (size_t)2560 * 2048; C = 512; bx = t & 15; by = t >> 4; }
    else                { int t = id - 6144; W = Wo; dst = WoT; C = 2048; bx = t & 63; by = t >> 6; fold = false; }
    const int c0 = bx * 32, r0 = by * 32;
    tile[ty][tx] = W[(size_t)(r0 + ty) * C + c0 + tx];
    if (fold) {
        if (tx < 16) As[ty][tx] = A[(r0 + ty) * 16 + tx];
        if (ty < 16) Bs[ty][tx] = Bm[(size_t)ty * C + c0 + tx];
    }
    __syncthreads();
    float v = tile[tx][ty];
    if (fold) {
        float acc = 0.0f;
#pragma unroll
        for (int rr = 0; rr < 16; ++rr) acc += As[tx][rr] * Bs[rr][ty];
        v += 2.0f * acc;
    }
    dst[(size_t)(c0 + ty) * 2048 + r0 + tx] = f2bf(v);
}

// ---------------- QKV GEMM: 256x192 tile, BK=64, 8 waves, 8-phase, FULL-CHIP grid ------
__global__ __launch_bounds__(512) void gemm256_qkv_kernel(
    const u16* __restrict__ A, const u16* __restrict__ Bt, u16* __restrict__ Cq,
    u16* __restrict__ Ck, u16* __restrict__ Vt, const u32* __restrict__ ropetbl) {
    constexpr int K = 2048, NT = 32;
    __shared__ u16 Asl[2][256 * 64];
    __shared__ u16 Bsl[2][192 * 64];
    const int tid = threadIdx.x;
    const int wid = tid >> 6, lane = tid & 63;
    const int flat = blockIdx.x;
    const int m = ((flat & 7) << 1) + ((flat >> 3) & 1);   // XCD m-chunking
    const int n = flat >> 4;
    const int mbase = m * 256, nbase = n * 192;
    const int wrow = (wid >> 2) * 128, wcol = (wid & 3) * 48;
    const int fr = lane & 15, hi = lane >> 4;
    const int rs2 = fr & 7;
    f32x4 acc[8][3] = {};
    short8 Af[4][2], Bf[3][2];
    const u16* Ag = A + (size_t)mbase * K;
    const u16* Bg = Bt + (size_t)nbase * K;

    auto HT = [&](int t, int j) {
        if (t >= NT) return;
        const int buf = t & 1;
        const bool isA = (j < 4);
        u16* l = isA ? &Asl[buf][0] : &Bsl[buf][0];
        const u16* g = isA ? Ag : Bg;
        const int rbase = (isA ? j : (j - 4)) * 64;
        const int row = rbase + (tid >> 3);
        const int sl = (tid & 7) ^ ((tid >> 3) & 7);
        gload_lds16(&g[(size_t)row * K + t * 64 + sl * 8],
                    &l[rbase * 64 + wid * 512]);
    };
    auto DSA = [&](int mo, int buf) {
#pragma unroll
        for (int mi = 0; mi < 4; ++mi)
#pragma unroll
            for (int ks = 0; ks < 2; ++ks)
                Af[mi][ks] = *(const short8*)&Asl[buf][(wrow + (mo + mi) * 16 + fr) * 64 +
                                                       (((ks * 4 + hi) ^ rs2) * 8)];
    };
    auto DSB = [&](int nlo, int nhi, int buf) {
#pragma unroll
        for (int ni = 0; ni < 3; ++ni) {
            if (ni < nlo || ni >= nhi) continue;
#pragma unroll
            for (int ks = 0; ks < 2; ++ks)
                Bf[ni][ks] = *(const short8*)&Bsl[buf][(wcol + ni * 16 + fr) * 64 +
                                                       (((ks * 4 + hi) ^ rs2) * 8)];
        }
    };
    auto MFq = [&](int mo, int nlo, int nhi) {
        __builtin_amdgcn_s_setprio(1);
#pragma unroll
        for (int mi = 0; mi < 4; ++mi)
#pragma unroll
            for (int ni = 0; ni < 3; ++ni) {
                if (ni < nlo || ni >= nhi) continue;
#pragma unroll
                for (int ks = 0; ks < 2; ++ks)
                    acc[mo + mi][ni] = mfma16(Af[mi][ks], Bf[ni][ks], acc[mo + mi][ni]);
            }
        __builtin_amdgcn_s_setprio(0);
    };

    HT(0, 0); HT(0, 1); HT(0, 2); HT(0, 3); HT(0, 4); HT(0, 5); HT(0, 6);
    HT(1, 0); HT(1, 1); HT(1, 2); HT(1, 3);
    asm volatile("s_waitcnt vmcnt(4)" ::: "memory");
    GBAR();

#pragma unroll 1
    for (int i = 0; i < NT / 2; ++i) {
        const int t = 2 * i;
        DSA(0, 0); DSB(0, 2, 0); HT(t + 1, 4); HT(t + 1, 5);
        GBAR(); LGW(); MFq(0, 0, 2); GBAR();
        DSB(2, 3, 0); HT(t + 1, 6);
        GBAR(); LGW(); MFq(0, 2, 3); GBAR();
        DSA(4, 0);
        GBAR(); LGW(); MFq(4, 0, 2); GBAR();
        HT(t + 2, 0); HT(t + 2, 1); HT(t + 2, 2); HT(t + 2, 3);
        GBAR(); LGW(); MFq(4, 2, 3);
        if (t + 2 < NT) { asm volatile("s_waitcnt vmcnt(4)" ::: "memory"); }
        else            { asm volatile("s_waitcnt vmcnt(0)" ::: "memory"); }
        GBAR();
        DSA(0, 1); DSB(0, 2, 1); HT(t + 2, 4); HT(t + 2, 5);
        GBAR(); LGW(); MFq(0, 0, 2); GBAR();
        DSB(2, 3, 1); HT(t + 2, 6);
        GBAR(); LGW(); MFq(0, 2, 3); GBAR();
        DSA(4, 1);
        GBAR(); LGW(); MFq(4, 0, 2); GBAR();
        HT(t + 3, 0); HT(t + 3, 1); HT(t + 3, 2); HT(t + 3, 3);
        GBAR(); LGW(); MFq(4, 2, 3);
        if (t + 3 < NT)          { asm volatile("s_waitcnt vmcnt(4)" ::: "memory"); }
        else if (i < NT / 2 - 1) { asm volatile("s_waitcnt vmcnt(0)" ::: "memory"); }
        GBAR();
    }

    const int rb = mbase + wrow + (hi << 2);
#pragma unroll
    for (int ni = 0; ni < 3; ++ni) {
        const int colc = nbase + wcol + ni * 16;
        if (colc >= 2560) {
            const int feat = colc - 2560 + fr;
#pragma unroll
            for (int mi = 0; mi < 8; ++mi) {
                u16x4 w;
#pragma unroll
                for (int j = 0; j < 4; ++j) w[j] = f2bf(acc[mi][ni][j]);
                *(u16x4*)&Vt[(size_t)feat * 4096 + rb + mi * 16] = w;
            }
        } else {
            u16* C; int cs, ccol; float scale;
            if (colc < 2048) { C = Cq; cs = 2048; ccol = colc + fr;        scale = SCL2; }
            else             { C = Ck; cs = 512;  ccol = colc - 2048 + fr; scale = 1.0f; }
            const bool odd = (lane & 1);
            const int i0 = ((colc & 63) >> 1) + (fr >> 1);
#pragma unroll
            for (int mi = 0; mi < 8; ++mi)
#pragma unroll
                for (int j = 0; j < 4; ++j) {
                    const int row = rb + mi * 16 + j;
                    u32 cspk = ropetbl[(row & 1023) * 32 + i0];
                    float cv = bf2f((u16)cspk), sv = bf2f((u16)(cspk >> 16));
                    float v = acc[mi][ni][j];
                    float p = __shfl_xor(v, 1);
                    float r = odd ? (p * sv + v * cv) : (v * cv - p * sv);
                    C[(size_t)row * cs + ccol] = f2bf(r * scale);
                }
        }
    }
}

// ---------------- Wo GEMM: 128x128, BK=64, dbuf DMA + counted vmcnt + T2 swizzle --------
template <int CN>
__global__ __launch_bounds__(256) void gemm_kernel(
    const u16* __restrict__ A, const u16* __restrict__ Bt, float* __restrict__ C0, int Nn) {
    constexpr int K = 2048;
    constexpr int NT = K / 64;
    __shared__ u16 As[2][128 * 64];
    __shared__ u16 Bs[2][128 * 64];
    const int tid = threadIdx.x;
    const int wid = tid >> 6, lane = tid & 63;
    const int flat = blockIdx.y * gridDim.x + blockIdx.x;
    const int xcd = flat & 7, local = flat >> 3;
    const int mbase = (((xcd & 3) << 3) + (local & 7)) * 128;
    const int nbase = ((xcd >> 2) * CN + (local >> 3)) * 128;
    const int wrow = (wid >> 1) * 64, wcol = (wid & 1) * 64;
    const int fr = lane & 15, hi = lane >> 4;
    const int l8 = lane >> 3;
    const int swc = ((lane & 7) ^ l8) * 8;
    const int rs = fr & 7;
    f32x4 acc[4][4] = {};
    const u16* Ag = A + (size_t)mbase * K;
    const u16* Bg = Bt + (size_t)nbase * K;

    auto STAGE = [&](int kt, int buf) {
#pragma unroll
        for (int i = 0; i < 4; ++i) {
            const int r8 = (i * 4 + wid) * 8;
            gload_lds16(&Ag[(size_t)(r8 + l8) * K + kt * 64 + swc], &As[buf][r8 * 64]);
            gload_lds16(&Bg[(size_t)(r8 + l8) * K + kt * 64 + swc], &Bs[buf][r8 * 64]);
        }
    };

    STAGE(0, 0);
    for (int kt = 0; kt < NT; ++kt) {
        const int cur = kt & 1;
        if (kt < NT - 1) {
            STAGE(kt + 1, cur ^ 1);
            asm volatile("s_waitcnt vmcnt(8)" ::: "memory");
        } else {
            asm volatile("s_waitcnt vmcnt(0)" ::: "memory");
        }
        __builtin_amdgcn_s_barrier();
#pragma unroll
        for (int ks = 0; ks < 2; ++ks) {
            short8 af[4], bfr[4];
#pragma unroll
            for (int i = 0; i < 4; ++i) {
                const int arow = wrow + i * 16 + fr;
                const int brow = wcol + i * 16 + fr;
                af[i]  = *(const short8*)&As[cur][arow * 64 + (((ks * 4 + hi) ^ rs) * 8)];
                bfr[i] = *(const short8*)&Bs[cur][brow * 64 + (((ks * 4 + hi) ^ rs) * 8)];
            }
#pragma unroll
            for (int mi = 0; mi < 4; ++mi)
#pragma unroll
                for (int ni = 0; ni < 4; ++ni)
                    acc[mi][ni] = mfma16(af[mi], bfr[ni], acc[mi][ni]);
        }
        __builtin_amdgcn_s_barrier();
    }
    const int rb = mbase + wrow + (hi << 2);
    const int cb = nbase + wcol + fr;
#pragma unroll
    for (int mi = 0; mi < 4; ++mi)
#pragma unroll
        for (int j = 0; j < 4; ++j) {
            const size_t ro = (size_t)(rb + mi * 16 + j) * Nn;
#pragma unroll
            for (int ni = 0; ni < 4; ++ni) C0[ro + cb + ni * 16] = acc[mi][ni][j];
        }
}

// ---------------- attention tile step ----------------
template <bool DIAG>
static __device__ __forceinline__ void attn_tile_step(
    const u16* __restrict__ Ksb, const u16* __restrict__ Vsb,
    const short8* qf, f32x4* o, float& m, float& l,
    int sq, int kvb, int wid, int fr, int hi) {
    f32x4 s[4];
    const int sw = fr & 7;
#pragma unroll
    for (int mi = 0; mi < 4; ++mi) {
        if (!DIAG || mi <= wid) {
            const int row = (mi * 16 + fr) * 64;
            short8 kf0 = *(const short8*)&Ksb[row + ((hi ^ sw) * 8)];
            short8 kf1 = *(const short8*)&Ksb[row + (((4 + hi) ^ sw) * 8)];
            f32x4 z = {};
            z = mfma16(kf0, qf[0], z);
            z = mfma16(kf1, qf[1], z);
#pragma unroll
            for (int j = 0; j < 4; ++j) {
                float val = z[j];
                if (DIAG && mi == wid && (kvb + mi * 16 + hi * 4 + j > sq)) val = -3.0e38f;
                s[mi][j] = val;
            }
        } else {
            s[mi][0] = -3.0e38f; s[mi][1] = -3.0e38f;
            s[mi][2] = -3.0e38f; s[mi][3] = -3.0e38f;
        }
    }
    float pmax = fmaxf(fmaxf(fmaxf(s[0][0], s[0][1]), fmaxf(s[0][2], s[0][3])),
                       fmaxf(fmaxf(s[1][0], s[1][1]), fmaxf(s[1][2], s[1][3])));
    pmax = fmaxf(pmax, fmaxf(fmaxf(fmaxf(s[2][0], s[2][1]), fmaxf(s[2][2], s[2][3])),
                             fmaxf(fmaxf(s[3][0], s[3][1]), fmaxf(s[3][2], s[3][3]))));
    pmax = fmaxf(pmax, __shfl_xor(pmax, 16));
    pmax = fmaxf(pmax, __shfl_xor(pmax, 32));
    if (__any(pmax > m + 8.0f)) {
        const float mnew = fmaxf(m, pmax);
        const float fsc = exp2f(m - mnew);
        l *= fsc;
        m = mnew;
#pragma unroll
        for (int dn = 0; dn < 4; ++dn)
#pragma unroll
            for (int j = 0; j < 4; ++j) o[dn][j] *= fsc;
    }
    float rs = 0.0f;
    u32 pk[4][2];
#pragma unroll
    for (int mi = 0; mi < 4; ++mi) {
        float p0 = exp2f(s[mi][0] - m);
        float p1 = exp2f(s[mi][1] - m);
        float p2 = exp2f(s[mi][2] - m);
        float p3 = exp2f(s[mi][3] - m);
        rs += (p0 + p1) + (p2 + p3);
        pk[mi][0] = cvtpk(p0, p1);
        pk[mi][1] = cvtpk(p2, p3);
    }
    rs += __shfl_xor(rs, 16);
    rs += __shfl_xor(rs, 32);
    l += rs;
    const int ksmax = DIAG ? (wid >> 1) : 1;
#pragma unroll
    for (int ks = 0; ks < 2; ++ks) {
        if (ks > ksmax) continue;
        u32 w0 = pk[2 * ks][0], w2 = pk[2 * ks + 1][0];
        u32 w1 = pk[2 * ks][1], w3 = pk[2 * ks + 1][1];
        asm volatile("v_permlane32_swap_b32 %0, %1" : "+v"(w0), "+v"(w2));
        asm volatile("v_permlane16_swap_b32 %0, %1" : "+v"(w0), "+v"(w2));
        asm volatile("v_permlane32_swap_b32 %0, %1" : "+v"(w1), "+v"(w3));
        asm volatile("v_permlane16_swap_b32 %0, %1" : "+v"(w1), "+v"(w3));
        union { u32 w[4]; short8 s8; } pu;
        pu.w[0] = w0; pu.w[1] = w1; pu.w[2] = w2; pu.w[3] = w3;
        short8 pf = pu.s8;
#pragma unroll
        for (int dn = 0; dn < 4; ++dn) {
            const int row = (dn * 16 + fr) * 64;
            short8 vf = *(const short8*)&Vsb[row + (((ks * 4 + hi) ^ sw) * 8)];
            o[dn] = mfma16(vf, pf, o[dn]);
        }
    }
}

// ---------------- causal GQA flash attention, 2 heads + paired q-tiles per block -------
__global__ __launch_bounds__(256) void attn_kernel(
    const u16* __restrict__ q, const u16* __restrict__ k, const u16* __restrict__ vt,
    u16* __restrict__ ctx) {
    __shared__ u16 Ks[2][64 * 64];
    __shared__ u16 Vs[2][64 * 64];
    const int flat = blockIdx.x + 8 * (blockIdx.y + 16 * blockIdx.z);
    const int c = flat & 7, t = flat >> 3;
    const int jp = t & 7;
    const int grp = c + 8 * (t >> 3);
    const int hp = grp & 15, b = grp >> 4;
    const int qtA = jp, qtB = 15 - jp;
    const int h0 = hp * 2;
    const int g = hp >> 1;
    const int tid = threadIdx.x, wid = tid >> 6, lane = tid & 63;
    const int fr = lane & 15, hi = lane >> 4, fk = hi * 8;
    const int sqA = qtA * 64 + wid * 16 + fr;
    const int sqB = qtB * 64 + wid * 16 + fr;
    short8 qA0[2], qB0[2], qA1[2], qB1[2];
    {
        const u16* pa = &q[((size_t)(b * 1024 + sqA)) * 2048 + h0 * 64];
        qA0[0] = *(const short8*)&pa[fk];      qA0[1] = *(const short8*)&pa[32 + fk];
        qA1[0] = *(const short8*)&pa[64 + fk]; qA1[1] = *(const short8*)&pa[96 + fk];
        const u16* pb = &q[((size_t)(b * 1024 + sqB)) * 2048 + h0 * 64];
        qB0[0] = *(const short8*)&pb[fk];      qB0[1] = *(const short8*)&pb[32 + fk];
        qB1[0] = *(const short8*)&pb[64 + fk]; qB1[1] = *(const short8*)&pb[96 + fk];
    }
    f32x4 oA0[4] = {}, oA1[4] = {}, oB0[4] = {}, oB1[4] = {};
    float mA0 = -3.0e38f, lA0 = 0.0f, mA1 = -3.0e38f, lA1 = 0.0f;
    float mB0 = -3.0e38f, lB0 = 0.0f, mB1 = -3.0e38f, lB1 = 0.0f;
    const u16* kbase = k + ((size_t)b * 1024) * 512 + g * 64;
    const u16* vbase = vt + ((size_t)(g * 64)) * 4096 + b * 1024;
    const int l8 = lane >> 3;
    const int sw8 = ((lane & 7) ^ l8) * 8;

    auto stage = [&](int kt, int buf) {
        const u16* kg = kbase + (size_t)(kt * 64) * 512;
        const u16* vg = vbase + kt * 64;
#pragma unroll
        for (int i = 0; i < 2; ++i) {
            const int r8 = (i * 4 + wid) * 8;
            gload_lds16(&kg[(size_t)(r8 + l8) * 512 + sw8], &Ks[buf][r8 * 64]);
            gload_lds16(&vg[(size_t)(r8 + l8) * 4096 + sw8], &Vs[buf][r8 * 64]);
        }
    };

    stage(0, 0);
    for (int kt = 0; kt <= qtB; ++kt) {
        const int cur = kt & 1;
        __syncthreads();
        if (kt < qtB) stage(kt + 1, cur ^ 1);
        const int kvb = kt * 64;
        if (kt < qtA) {
            attn_tile_step<false>(Ks[cur], Vs[cur], qA0, oA0, mA0, lA0, sqA, kvb, wid, fr, hi);
            attn_tile_step<false>(Ks[cur], Vs[cur], qA1, oA1, mA1, lA1, sqA, kvb, wid, fr, hi);
        } else if (kt == qtA) {
            attn_tile_step<true>(Ks[cur], Vs[cur], qA0, oA0, mA0, lA0, sqA, kvb, wid, fr, hi);
            attn_tile_step<true>(Ks[cur], Vs[cur], qA1, oA1, mA1, lA1, sqA, kvb, wid, fr, hi);
        }
        if (kt < qtB) {
            attn_tile_step<false>(Ks[cur], Vs[cur], qB0, oB0, mB0, lB0, sqB, kvb, wid, fr, hi);
            attn_tile_step<false>(Ks[cur], Vs[cur], qB1, oB1, mB1, lB1, sqB, kvb, wid, fr, hi);
        } else {
            attn_tile_step<true>(Ks[cur], Vs[cur], qB0, oB0, mB0, lB0, sqB, kvb, wid, fr, hi);
            attn_tile_step<true>(Ks[cur], Vs[cur], qB1, oB1, mB1, lB1, sqB, kvb, wid, fr, hi);
        }
    }
    auto emit = [&](const f32x4* o, float l, int sq, int h) {
        const float linv = 1.0f / l;
        const size_t obase = ((size_t)(b * 1024 + sq)) * 2048 + h * 64;
#pragma unroll
        for (int dn = 0; dn < 4; ++dn) {
            u16x4 w;
#pragma unroll
            for (int j = 0; j < 4; ++j) w[j] = f2bf(o[dn][j] * linv);
            *(u16x4*)&ctx[obase + dn * 16 + hi * 4] = w;
        }
    };
    emit(oA0, lA0, sqA, h0);
    emit(oA1, lA1, sqA, h0 + 1);
    emit(oB0, lB0, sqB, h0);
    emit(oB1, lB1, sqB, h0 + 1);
}

extern "C" void kernel_launch(void* const* d_in, const int* in_sizes, int n_in,
                              void* d_out, int out_size, void* d_ws, size_t ws_size,
                              hipStream_t stream) {
    const float* x    = (const float*)d_in[0];
    const float* fcos = (const float*)d_in[1];
    const float* fsin = (const float*)d_in[2];
    const float* Wq   = (const float*)d_in[3];
    const float* Wk   = (const float*)d_in[4];
    const float* Wv   = (const float*)d_in[5];
    const float* Wo   = (const float*)d_in[6];
    const float* qA   = (const float*)d_in[7];
    const float* qB   = (const float*)d_in[8];
    const float* kA   = (const float*)d_in[9];
    const float* kB   = (const float*)d_in[10];
    const float* vA   = (const float*)d_in[11];
    const float* vB   = (const float*)d_in[12];
    float* out = (float*)d_out;

    char* ws = (char*)d_ws;
    size_t off = 0;
    auto alloc = [&](size_t bytes) { char* p = ws + off; off += (bytes + 255) & ~(size_t)255; return p; };
    u16* xb     = (u16*)alloc((size_t)4096 * 2048 * 2);
    u16* WqkvT  = (u16*)alloc((size_t)3072 * 2048 * 2);
    u16* WoT    = (u16*)alloc((size_t)2048 * 2048 * 2);
    u16* qbuf   = (u16*)alloc((size_t)4096 * 2048 * 2);
    u16* kbuf   = (u16*)alloc((size_t)4096 * 512 * 2);
    u16* VT2    = (u16*)alloc((size_t)512 * 4096 * 2);   // V^T: [(g*64+d)][b*1024+s]
    u16* ctx    = (u16*)alloc((size_t)4096 * 2048 * 2);
    u32* rtbl   = (u32*)alloc((size_t)1024 * 32 * 4);

    // cast x + rope pack + ALL weight prep in ONE dispatch
    prep_all_kernel<<<12296, dim3(32, 32), 0, stream>>>(
        x, fcos, fsin, Wq, Wk, Wv, Wo, qA, qB, kA, kB, vA, vB,
        xb, rtbl, WqkvT, WoT);

    // QKV projection: 256x192 8-phase, 256 blocks (full chip), fused RoPE + V^T epilogue
    gemm256_qkv_kernel<<<dim3(256), 512, 0, stream>>>(xb, WqkvT, qbuf, kbuf, VT2, rtbl);

    attn_kernel<<<dim3(8, 16, 4), 256, 0, stream>>>(qbuf, kbuf, VT2, ctx);

    // Wo projection: 128x128 dbuf (proven — exactly one 8-phase kernel per iteration)
    gemm_kernel<8><<<dim3(32, 16), 256, 0, stream>>>(ctx, WoT, out, 2048);
}